// Round 25
// baseline (183.656 us; speedup 1.0000x reference)
//
#include <hip/hip_runtime.h>

#define N_CODES 512
#define D 32
#define NVEC (8192 * 64)          // 524288 vectors
#define ZQ_ELEMS (NVEC * D)
#define BT 512                    // main block threads (8 waves share LDS image)
#define NBLK (NVEC / BT)          // 1024 main blocks
#define MARGIN_TRIG 7e-5f
#define SA (-1.0f / 16.0f)        // B = SA*z   (power of 2, exact)
#define SB (32.0f)                // A = SB*w   -> A*B sums to -2 z.w
#define KMASK5 0xFFFFFFE0u        // clear 5 low mantissa bits for t tag

typedef _Float16 half8 __attribute__((ext_vector_type(8)));
typedef float f32x4 __attribute__((ext_vector_type(4)));

// ws: @8 uint flagcnt | @64 float ww[512] | @2112 float ww1[512]
//     | @4160 bfrag (32768) | @36928 float wT[32][512] (65536)
//     | @102464 double partials[1024] | @118848 int worklist[...]
#define WW1_OFF 2112
#define BFRAG_OFF 4160
#define WT_OFF 36928
#define PART_OFF 102464
#define WL_OFF 118848
#define STAGE_F4 2176             // (2048 + 32768) / 16, staged from ws+2112

__device__ __forceinline__ unsigned umin_(unsigned a, unsigned b) { return a < b ? a : b; }
__device__ __forceinline__ unsigned umax_(unsigned a, unsigned b) { return a > b ? a : b; }

// prep: coalesced wT float4 stores (R21-validated)
__global__ void vq_prep(const float* __restrict__ cb, float* __restrict__ ww,
                        float* __restrict__ ww1, half8* __restrict__ bfrag,
                        float* __restrict__ wT, unsigned* __restrict__ flagcnt) {
    int gid = blockIdx.x * 256 + threadIdx.x;   // 16 x 256 = 4096
    if (gid == 0) *flagcnt = 0u;
    {   // wT[d][c]: 4 consecutive c per thread -> coalesced float4 store
        int flat = gid * 4;                     // 16384 floats total
        int d = flat >> 9, c = flat & 511;
        float4 v;
        v.x = cb[(size_t)(c + 0) * D + d];
        v.y = cb[(size_t)(c + 1) * D + d];
        v.z = cb[(size_t)(c + 2) * D + d];
        v.w = cb[(size_t)(c + 3) * D + d];
        *(float4*)(wT + flat) = v;
    }
    if (gid < 2048) {                           // MFMA A-operand fragments
        int t = gid >> 6, l = gid & 63;
        int code = t * 16 + (l & 15), koff = (l >> 4) * 8;
        const float* w = cb + (size_t)code * D + koff;
        half8 h;
#pragma unroll
        for (int j = 0; j < 8; ++j) h[j] = (_Float16)(SB * w[j]);
        bfrag[t * 64 + l] = h;
    }
    if (gid < N_CODES) {                        // platonic ||w||^2 -> f32
        const float* wr = cb + (size_t)gid * D;
        double s = 0.0;
#pragma unroll
        for (int d = 0; d < D; ++d) s = fma((double)wr[d], (double)wr[d], s);
        ww[gid] = (float)s;                     // exact, for fixup formula
        ww1[gid] = (float)(1.0 + s);            // C-init (+1 => scores positive)
    }
}

// Loop-INVERTED transposed-MFMA main (R23 structure, validated-correct): all 4
// Bz live; per t-pair ONE W0/W1/cv0/cv1 LDS read feeds 8 independent MFMAs.
// LDS reads/wave 256 -> 64; 8-deep MFMA ILP; 16 independent (vt,r) min-chains.
// amdgpu_waves_per_eu(3,4) pins the allocator OUT of the 64-reg/8-wave bucket
// (R23 failure: launch_bounds min-only -> allocator chose 64 VGPR + spills,
// FETCH 183MB, WRITE 367MB). Target: ~110 VGPR, zero spill.
__global__ __launch_bounds__(BT)
__attribute__((amdgpu_waves_per_eu(3, 4)))
void vq_main(
        const float* __restrict__ z, const float* __restrict__ cbf,
        const float4* __restrict__ stage_src,   // ws+2112: ww1 | bfrag
        float* __restrict__ zq, float* __restrict__ idxo,
        double* __restrict__ partials, unsigned* __restrict__ flagcnt,
        int* __restrict__ worklist, int wl_cap) {
    __shared__ __align__(16) char smem[43008];  // cin 2K | bfrag 32K | scratch 8K
    __shared__ double wsum[8];
    const int tid = threadIdx.x;
    const int l = tid & 63, wv = tid >> 6;
    const int g16 = l & 15, kg = l >> 4, koff = kg * 8;
    const int vblock = blockIdx.x * BT;                  // block owns 512 rows
    const int vwave = vblock + wv * 64;                  // wave owns 64 rows

    // issue ALL 8 z loads up front (latency hides under staging + barrier)
    float4 za[4][2];
#pragma unroll
    for (int vt = 0; vt < 4; ++vt) {
        const float* zp = z + (size_t)(vwave + vt * 16 + g16) * D + koff;
        za[vt][0] = *(const float4*)zp;
        za[vt][1] = *(const float4*)(zp + 4);
    }

    {   // stage ww1 + code fragments into LDS
        float4* s4 = (float4*)smem;
#pragma unroll
        for (int i = 0; i < 5; ++i) {
            int k = i * BT + tid;
            if (k < STAGE_F4) s4[k] = stage_src[k];
        }
    }
    const float* lds_cin = (const float*)smem;           // 1+||w||^2 [512]
    const char* lds_bf = smem + 2048;                    // A fragments (32KB)
    float4* scratch = (float4*)(smem + 34816);           // [512] (m1,m2,idx,zz)

    // convert to fragments + ||z||^2 PARTIALS (summed once in the reduce)
    half8 Bz[4];
    float ss[4];
#pragma unroll
    for (int vt = 0; vt < 4; ++vt) {
        float4 x0 = za[vt][0], x1 = za[vt][1];
        Bz[vt][0] = (_Float16)(x0.x * SA); Bz[vt][1] = (_Float16)(x0.y * SA);
        Bz[vt][2] = (_Float16)(x0.z * SA); Bz[vt][3] = (_Float16)(x0.w * SA);
        Bz[vt][4] = (_Float16)(x1.x * SA); Bz[vt][5] = (_Float16)(x1.y * SA);
        Bz[vt][6] = (_Float16)(x1.z * SA); Bz[vt][7] = (_Float16)(x1.w * SA);
        float s = 0.f;
        s = fmaf(x0.x, x0.x, s); s = fmaf(x0.y, x0.y, s);
        s = fmaf(x0.z, x0.z, s); s = fmaf(x0.w, x0.w, s);
        s = fmaf(x1.x, x1.x, s); s = fmaf(x1.y, x1.y, s);
        s = fmaf(x1.z, x1.z, s); s = fmaf(x1.w, x1.w, s);
        ss[vt] = s;                 // PARTIAL (8 elems); butterfly sums it once
    }

    __syncthreads();   // staging visible

    unsigned m1s[4][4], m2s[4][4];
#pragma unroll
    for (int vt = 0; vt < 4; ++vt)
#pragma unroll
        for (int r = 0; r < 4; ++r) { m1s[vt][r] = 0xFFFFFFFFu; m2s[vt][r] = 0xFFFFFFFFu; }

    // t-pair loop: ONE W0/W1/cv0/cv1 read -> 8 MFMAs (all 4 vt x 2 parities)
#pragma unroll
    for (int tp = 0; tp < 16; ++tp) {
        half8 W0 = *(const half8*)(lds_bf + (2 * tp) * 1024 + l * 16);
        half8 W1 = *(const half8*)(lds_bf + (2 * tp + 1) * 1024 + l * 16);
        f32x4 cv0 = *(const f32x4*)(lds_cin + (2 * tp) * 16 + kg * 4);
        f32x4 cv1 = *(const f32x4*)(lds_cin + (2 * tp + 1) * 16 + kg * 4);
        f32x4 acc0[4], acc1[4];
#pragma unroll
        for (int vt = 0; vt < 4; ++vt) {
            acc0[vt] = __builtin_amdgcn_mfma_f32_16x16x32_f16(W0, Bz[vt], cv0, 0, 0, 0);
            acc1[vt] = __builtin_amdgcn_mfma_f32_16x16x32_f16(W1, Bz[vt], cv1, 0, 0, 0);
        }
#pragma unroll
        for (int vt = 0; vt < 4; ++vt)
#pragma unroll
            for (int r = 0; r < 4; ++r) {
                unsigned k0 = (__float_as_uint(acc0[vt][r]) & KMASK5) | (unsigned)(2 * tp);
                unsigned k1 = (__float_as_uint(acc1[vt][r]) & KMASK5) | (unsigned)(2 * tp + 1);
                unsigned med;
                asm("v_med3_u32 %0, %1, %2, %3"
                    : "=v"(med) : "v"(m1s[vt][r]), "v"(k0), "v"(k1));
                asm("v_min3_u32 %0, %1, %2, %3"
                    : "=v"(m1s[vt][r]) : "v"(m1s[vt][r]), "v"(k0), "v"(k1));
                m2s[vt][r] = umin_(m2s[vt][r], med);
            }
    }

    // per-vt: merge 4 r-chains, cross-kg reduce, store row table
#pragma unroll
    for (int vt = 0; vt < 4; ++vt) {
        unsigned a01 = umin_(m1s[vt][0], m1s[vt][1]), x01 = umax_(m1s[vt][0], m1s[vt][1]);
        unsigned a23 = umin_(m1s[vt][2], m1s[vt][3]), x23 = umax_(m1s[vt][2], m1s[vt][3]);
        unsigned b1 = umin_(a01, a23);
        unsigned sec = umin_(umax_(a01, a23), umin_(x01, x23));  // 2nd-min of m1s
        unsigned m2all = umin_(umin_(m2s[vt][0], m2s[vt][1]),
                               umin_(m2s[vt][2], m2s[vt][3]));
        unsigned b2 = umin_(sec, m2all);
        int rwin = (m1s[vt][0] == b1) ? 0
                 : (m1s[vt][1] == b1) ? 1
                 : (m1s[vt][2] == b1) ? 2 : 3;
        unsigned mymin = b1;
        float ssv = ss[vt];

        // cross-kg reduce (lanes +-16, +-32): b1, b2, ss
#pragma unroll
        for (int dd = 16; dd <= 32; dd <<= 1) {
            unsigned o1 = __shfl_xor(b1, dd, 64);
            unsigned o2 = __shfl_xor(b2, dd, 64);
            float os = __shfl_xor(ssv, dd, 64);
            b2 = umin_(umin_(b2, o2), umax_(b1, o1));
            b1 = umin_(b1, o1);
            ssv += os;
        }
        // winner kg via ballot (lowest kg on tie), then winner lane's r
        unsigned long long bal =
            __ballot(mymin == b1) & (0x0001000100010001ull << g16);
        int firstl = __builtin_ctzll(bal);
        int rw = __shfl(rwin, firstl, 64);
        int code = (int)(b1 & 31u) * 16 + (firstl >> 4) * 4 + rw;
        if (kg == 0)
            scratch[wv * 64 + vt * 16 + g16] =
                make_float4(__uint_as_float(b1 & KMASK5),
                            __uint_as_float(b2 & KMASK5),
                            __int_as_float(code), ssv);
    }
    __syncthreads();

    // ---- epilogue (block scope) ----
    float4 my = scratch[tid];                    // row tid of this block
    int bai = __float_as_int(my.z);

    // near-tie rows -> dense worklist (one uint atomic per wave)
    {
        bool flag = (my.y - my.x) <= MARGIN_TRIG;
        unsigned long long mask = __ballot(flag);
        if (mask) {
            int base = 0;
            if (l == 0) base = (int)atomicAdd(flagcnt, (unsigned)__popcll(mask));
            base = __shfl(base, 0, 64);
            if (flag) {
                int pos = base + (int)__popcll(mask & ((1ull << l) - 1ull));
                if (pos < wl_cap) worklist[pos] = vblock + tid;
            }
        }
    }

    // loss: ||z-q||^2 = ||z||^2 + (m1 - 1)
    {
        double contrib = ((double)my.x - 1.0) + (double)my.w;
#pragma unroll
        for (int off = 32; off; off >>= 1) contrib += __shfl_down(contrib, off, 64);
        if (l == 0) wsum[wv] = contrib;
    }
    __syncthreads();
    if (tid == 0) {
        double s = 0.0;
#pragma unroll
        for (int w = 0; w < 8; ++w) s += wsum[w];
        partials[blockIdx.x] = s;
    }

    // indices: 2KB contiguous per block
    idxo[vblock + tid] = (float)bai;

    // z_q: 512 threads x 8 iters cover 512 rows x 32 floats, fully contiguous
    {
        const float4* cb4 = (const float4*)cbf;
        float4* zq4 = (float4*)zq;
        const int c = tid & 7;
#pragma unroll
        for (int it = 0; it < 8; ++it) {
            int r = it * 64 + (tid >> 3);
            int win = __float_as_int(scratch[r].z);
            float4 val = cb4[(size_t)win * 8 + c];
            zq4[(size_t)(vblock + r) * 8 + c] = val;
        }
    }
}

// cold path: LDS-staged wT + full wave parallelism (R21-validated).
// Block 0 also does the final loss reduction.
__global__ __launch_bounds__(512, 2) void vq_fixup(
        const float* __restrict__ z, const float* __restrict__ cbf,
        const float* __restrict__ wT, const float* __restrict__ c32g,
        float* __restrict__ zq, float* __restrict__ idxo,
        const unsigned* __restrict__ flagcnt,
        const int* __restrict__ worklist, int wl_cap,
        const double* __restrict__ partials, float* __restrict__ loss_out) {
    __shared__ __align__(16) float wl_lds[D * N_CODES];  // 64KB
    __shared__ double w4[4];
    const int tid = threadIdx.x;

    {   // stage wT into LDS: 4096 float4 over 512 threads
        float4* s4 = (float4*)wl_lds;
        const float4* g4 = (const float4*)wT;
#pragma unroll
        for (int i = 0; i < 8; ++i) s4[i * 512 + tid] = g4[i * 512 + tid];
    }

    if (blockIdx.x == 0 && tid < 256) {         // final loss reduction
        double s = 0.0;
#pragma unroll
        for (int i = 0; i < NBLK / 256; ++i) s += partials[i * 256 + tid];
#pragma unroll
        for (int off = 32; off; off >>= 1) s += __shfl_down(s, off, 64);
        if ((tid & 63) == 0) w4[tid >> 6] = s;
    }
    __syncthreads();                            // staging + w4 visible
    if (blockIdx.x == 0 && tid == 0)
        *loss_out = (float)(1.25 * (w4[0] + w4[1] + w4[2] + w4[3])
                            / (double)ZQ_ELEMS);

    int cnt = (int)*flagcnt; if (cnt > wl_cap) cnt = wl_cap;
    const int l = tid & 63;
    const int wave = (blockIdx.x * 512 + tid) >> 6;
    const int nwaves = (gridDim.x * 512) >> 6;

    for (int e = wave; e < cnt; e += nwaves) {
        int v = worklist[e];
        const float* zv = z + (size_t)v * D;        // uniform addr -> broadcast
        float zd[D];
#pragma unroll
        for (int q = 0; q < 8; ++q) {
            float4 t = *(const float4*)(zv + q * 4);
            zd[4 * q + 0] = t.x; zd[4 * q + 1] = t.y;
            zd[4 * q + 2] = t.z; zd[4 * q + 3] = t.w;
        }
        double Ad = 0.0;
#pragma unroll
        for (int d = 0; d < D; ++d) Ad = fma((double)zd[d], (double)zd[d], Ad);
        float Af = (float)Ad;

        // 8 codes per lane: c = l + 64k ; LDS rows, lane-consecutive reads
        double bd[8];
#pragma unroll
        for (int k = 0; k < 8; ++k) bd[k] = 0.0;
#pragma unroll 4
        for (int d = 0; d < D; ++d) {
            double zdd = (double)zd[d];
            const float* wrow = wl_lds + d * N_CODES + l;
#pragma unroll
            for (int k = 0; k < 8; ++k)
                bd[k] = fma(zdd, (double)wrow[64 * k], bd[k]);
        }
        float best = 1e30f; int bi = 0;
#pragma unroll
        for (int k = 0; k < 8; ++k) {
            int c = l + 64 * k;
            float B32 = (float)bd[k];               // platonic dot
            float dq = __fadd_rn(__fsub_rn(Af, __fmul_rn(2.0f, B32)), c32g[c]);
            if (dq < best) { best = dq; bi = c; }   // k asc => c asc: first-index
        }
#pragma unroll
        for (int dd = 1; dd < 64; dd <<= 1) {
            float ob = __shfl_xor(best, dd, 64);
            int obi = __shfl_xor(bi, dd, 64);
            bool take = (ob < best) || (ob == best && obi < bi);
            best = take ? ob : best; bi = take ? obi : bi;
        }
        if (l == 0) idxo[v] = (float)bi;
        if (l < 8) {                                // one full 128B line
            float4 val = ((const float4*)cbf)[(size_t)bi * 8 + l];
            ((float4*)zq)[(size_t)v * 8 + l] = val;
        }
    }
}

extern "C" void kernel_launch(void* const* d_in, const int* in_sizes, int n_in,
                              void* d_out, int out_size, void* d_ws, size_t ws_size,
                              hipStream_t stream) {
    const float* z  = (const float*)d_in[0];
    const float* cb = (const float*)d_in[1];
    float* out  = (float*)d_out;
    float* zq   = out;
    float* idxo = out + ZQ_ELEMS;
    float* loss = out + ZQ_ELEMS + NVEC;
    unsigned* flagcnt = (unsigned*)((char*)d_ws + 8);
    float*  ww   = (float*)((char*)d_ws + 64);
    float*  ww1  = (float*)((char*)d_ws + WW1_OFF);
    half8*  bfrag = (half8*)((char*)d_ws + BFRAG_OFF);
    float*  wT   = (float*)((char*)d_ws + WT_OFF);
    const float4* stage_src = (const float4*)((char*)d_ws + WW1_OFF);
    double* partials = (double*)((char*)d_ws + PART_OFF);
    int*    worklist = (int*)((char*)d_ws + WL_OFF);
    long long avail = (long long)ws_size - WL_OFF;
    int wl_cap = avail > 0 ? (int)(avail / 4 < NVEC ? avail / 4 : NVEC) : 0;

    vq_prep<<<16, 256, 0, stream>>>(cb, ww, ww1, bfrag, wT, flagcnt);
    vq_main<<<NBLK, BT, 0, stream>>>(z, cb, stage_src, zq, idxo,
                                     partials, flagcnt, worklist, wl_cap);
    vq_fixup<<<512, 512, 0, stream>>>(z, cb, wT, ww, zq, idxo,
                                      flagcnt, worklist, wl_cap, partials, loss);
}

// Round 26
// 117.765 us; speedup vs baseline: 1.5595x; 1.5595x over previous
//
#include <hip/hip_runtime.h>

#define N_CODES 512
#define D 32
#define NVEC (8192 * 64)          // 524288 vectors
#define ZQ_ELEMS (NVEC * D)
#define BT 512                    // main block threads (8 waves share LDS image)
#define TILES 2                   // tiles of 512 rows per persistent block
#define NBLK (NVEC / (BT * TILES))   // 512 blocks = exactly 2/CU, one generation
#define MARGIN_TRIG 7e-5f
#define SA (-1.0f / 16.0f)        // B = SA*z   (power of 2, exact)
#define SB (32.0f)                // A = SB*w   -> A*B sums to -2 z.w
#define KMASK5 0xFFFFFFE0u        // clear 5 low mantissa bits for t tag

typedef _Float16 half8 __attribute__((ext_vector_type(8)));
typedef float f32x4 __attribute__((ext_vector_type(4)));

// ws: @8 uint flagcnt | @64 float ww[512] | @2112 float ww1[512]
//     | @4160 bfrag (32768) | @36928 float wT[32][512] (65536)
//     | @102464 double partials[1024] | @118848 int worklist[...]
#define WW1_OFF 2112
#define BFRAG_OFF 4160
#define WT_OFF 36928
#define PART_OFF 102464
#define WL_OFF 118848
#define STAGE_F4 2176             // (2048 + 32768) / 16, staged from ws+2112

__device__ __forceinline__ unsigned umin_(unsigned a, unsigned b) { return a < b ? a : b; }
__device__ __forceinline__ unsigned umax_(unsigned a, unsigned b) { return a > b ? a : b; }

// prep: coalesced wT float4 stores (R21-validated)
__global__ void vq_prep(const float* __restrict__ cb, float* __restrict__ ww,
                        float* __restrict__ ww1, half8* __restrict__ bfrag,
                        float* __restrict__ wT, unsigned* __restrict__ flagcnt) {
    int gid = blockIdx.x * 256 + threadIdx.x;   // 16 x 256 = 4096
    if (gid == 0) *flagcnt = 0u;
    {   // wT[d][c]: 4 consecutive c per thread -> coalesced float4 store
        int flat = gid * 4;                     // 16384 floats total
        int d = flat >> 9, c = flat & 511;
        float4 v;
        v.x = cb[(size_t)(c + 0) * D + d];
        v.y = cb[(size_t)(c + 1) * D + d];
        v.z = cb[(size_t)(c + 2) * D + d];
        v.w = cb[(size_t)(c + 3) * D + d];
        *(float4*)(wT + flat) = v;
    }
    if (gid < 2048) {                           // MFMA A-operand fragments
        int t = gid >> 6, l = gid & 63;
        int code = t * 16 + (l & 15), koff = (l >> 4) * 8;
        const float* w = cb + (size_t)code * D + koff;
        half8 h;
#pragma unroll
        for (int j = 0; j < 8; ++j) h[j] = (_Float16)(SB * w[j]);
        bfrag[t * 64 + l] = h;
    }
    if (gid < N_CODES) {                        // platonic ||w||^2 -> f32
        const float* wr = cb + (size_t)gid * D;
        double s = 0.0;
#pragma unroll
        for (int d = 0; d < D; ++d) s = fma((double)wr[d], (double)wr[d], s);
        ww[gid] = (float)s;                     // exact, for fixup formula
        ww1[gid] = (float)(1.0 + s);            // C-init (+1 => scores positive)
    }
}

// Transposed MFMA main (R20/R22/R24 hot loop) as PERSISTENT 2-tile blocks:
// 512 blocks x 512 thr = exactly 2 blocks/CU, fully resident, single
// generation (no 256-block tail at 1/3 width) and LDS staging amortized 2x.
__global__ __launch_bounds__(BT, 6) void vq_main(
        const float* __restrict__ z, const float* __restrict__ cbf,
        const float4* __restrict__ stage_src,   // ws+2112: ww1 | bfrag
        float* __restrict__ zq, float* __restrict__ idxo,
        double* __restrict__ partials, unsigned* __restrict__ flagcnt,
        int* __restrict__ worklist, int wl_cap) {
    __shared__ __align__(16) char smem[43008];  // cin 2K | bfrag 32K | scratch 8K
    __shared__ double wsum[8];
    const int tid = threadIdx.x;

    {   // stage ww1 + code fragments into LDS (ONCE for both tiles)
        float4* s4 = (float4*)smem;
#pragma unroll
        for (int i = 0; i < 5; ++i) {
            int k = i * BT + tid;
            if (k < STAGE_F4) s4[k] = stage_src[k];
        }
    }
    const float* lds_cin = (const float*)smem;           // 1+||w||^2 [512]
    const char* lds_bf = smem + 2048;                    // A fragments (32KB)
    float4* scratch = (float4*)(smem + 34816);           // [512] (m1,m2,idx,zz)

    const int l = tid & 63, wv = tid >> 6;
    const int g16 = l & 15, kg = l >> 4, koff = kg * 8;

    __syncthreads();   // staging visible

#pragma unroll 1
    for (int tt = 0; tt < TILES; ++tt) {
        const int tile = blockIdx.x * TILES + tt;
        const int vblock = tile * BT;                    // tile owns 512 rows
        const int vwave = vblock + wv * 64;              // wave owns 64 rows

#pragma unroll 1
        for (int vt = 0; vt < 4; ++vt) {
            const float* zp = z + (size_t)(vwave + vt * 16 + g16) * D + koff;
            float4 a0 = *(const float4*)zp;
            float4 a1 = *(const float4*)(zp + 4);
            half8 Bz;
            Bz[0] = (_Float16)(a0.x * SA); Bz[1] = (_Float16)(a0.y * SA);
            Bz[2] = (_Float16)(a0.z * SA); Bz[3] = (_Float16)(a0.w * SA);
            Bz[4] = (_Float16)(a1.x * SA); Bz[5] = (_Float16)(a1.y * SA);
            Bz[6] = (_Float16)(a1.z * SA); Bz[7] = (_Float16)(a1.w * SA);
            float ss = 0.f;                              // ||z||^2 partial
            ss = fmaf(a0.x, a0.x, ss); ss = fmaf(a0.y, a0.y, ss);
            ss = fmaf(a0.z, a0.z, ss); ss = fmaf(a0.w, a0.w, ss);
            ss = fmaf(a1.x, a1.x, ss); ss = fmaf(a1.y, a1.y, ss);
            ss = fmaf(a1.z, a1.z, ss); ss = fmaf(a1.w, a1.w, ss);
            // ss stays PARTIAL; the cross-kg butterfly sums it exactly once.

            unsigned m1c[4], m2c[4];
#pragma unroll
            for (int r = 0; r < 4; ++r) { m1c[r] = 0xFFFFFFFFu; m2c[r] = 0xFFFFFFFFu; }

            // fully unrolled t-pair loop => t literal => inline-const tag
#pragma unroll
            for (int tp = 0; tp < 16; ++tp) {
                half8 W0 = *(const half8*)(lds_bf + (2 * tp) * 1024 + l * 16);
                half8 W1 = *(const half8*)(lds_bf + (2 * tp + 1) * 1024 + l * 16);
                f32x4 cv0 = *(const f32x4*)(lds_cin + (2 * tp) * 16 + kg * 4);
                f32x4 cv1 = *(const f32x4*)(lds_cin + (2 * tp + 1) * 16 + kg * 4);
                f32x4 acc0 = __builtin_amdgcn_mfma_f32_16x16x32_f16(W0, Bz, cv0, 0, 0, 0);
                f32x4 acc1 = __builtin_amdgcn_mfma_f32_16x16x32_f16(W1, Bz, cv1, 0, 0, 0);
#pragma unroll
                for (int r = 0; r < 4; ++r) {
                    unsigned k0 = (__float_as_uint(acc0[r]) & KMASK5) | (unsigned)(2 * tp);
                    unsigned k1 = (__float_as_uint(acc1[r]) & KMASK5) | (unsigned)(2 * tp + 1);
                    unsigned med;
                    asm("v_med3_u32 %0, %1, %2, %3"
                        : "=v"(med) : "v"(m1c[r]), "v"(k0), "v"(k1));
                    asm("v_min3_u32 %0, %1, %2, %3"
                        : "=v"(m1c[r]) : "v"(m1c[r]), "v"(k0), "v"(k1));
                    m2c[r] = umin_(m2c[r], med);
                }
            }

            // merge the 4 chains -> lane-local (b1, b2, rwin)
            unsigned a01 = umin_(m1c[0], m1c[1]), x01 = umax_(m1c[0], m1c[1]);
            unsigned a23 = umin_(m1c[2], m1c[3]), x23 = umax_(m1c[2], m1c[3]);
            unsigned b1 = umin_(a01, a23);
            unsigned sec = umin_(umax_(a01, a23), umin_(x01, x23));
            unsigned m2all = umin_(umin_(m2c[0], m2c[1]), umin_(m2c[2], m2c[3]));
            unsigned b2 = umin_(sec, m2all);
            int rwin = (m1c[0] == b1) ? 0
                     : (m1c[1] == b1) ? 1
                     : (m1c[2] == b1) ? 2 : 3;
            unsigned mymin = b1;

            // cross-kg reduce (lanes +-16, +-32): b1, b2, ss
#pragma unroll
            for (int dd = 16; dd <= 32; dd <<= 1) {
                unsigned o1 = __shfl_xor(b1, dd, 64);
                unsigned o2 = __shfl_xor(b2, dd, 64);
                float os = __shfl_xor(ss, dd, 64);
                b2 = umin_(umin_(b2, o2), umax_(b1, o1));
                b1 = umin_(b1, o1);
                ss += os;
            }
            // winner kg via ballot (lowest kg on tie), then winner lane's r
            unsigned long long bal =
                __ballot(mymin == b1) & (0x0001000100010001ull << g16);
            int firstl = __builtin_ctzll(bal);
            int rw = __shfl(rwin, firstl, 64);
            int code = (int)(b1 & 31u) * 16 + (firstl >> 4) * 4 + rw;
            if (kg == 0)
                scratch[wv * 64 + vt * 16 + g16] =
                    make_float4(__uint_as_float(b1 & KMASK5),
                                __uint_as_float(b2 & KMASK5),
                                __int_as_float(code), ss);
        }
        __syncthreads();

        // ---- per-tile epilogue (block scope) ----
        float4 my = scratch[tid];                // row tid of this tile
        int bai = __float_as_int(my.z);

        // near-tie rows -> dense worklist (one uint atomic per wave)
        {
            bool flag = (my.y - my.x) <= MARGIN_TRIG;
            unsigned long long mask = __ballot(flag);
            if (mask) {
                int base = 0;
                if (l == 0) base = (int)atomicAdd(flagcnt, (unsigned)__popcll(mask));
                base = __shfl(base, 0, 64);
                if (flag) {
                    int pos = base + (int)__popcll(mask & ((1ull << l) - 1ull));
                    if (pos < wl_cap) worklist[pos] = vblock + tid;
                }
            }
        }

        // loss: ||z-q||^2 = ||z||^2 + (m1 - 1)
        {
            double contrib = ((double)my.x - 1.0) + (double)my.w;
#pragma unroll
            for (int off = 32; off; off >>= 1) contrib += __shfl_down(contrib, off, 64);
            if (l == 0) wsum[wv] = contrib;
        }
        __syncthreads();
        if (tid == 0) {
            double s = 0.0;
#pragma unroll
            for (int w = 0; w < 8; ++w) s += wsum[w];
            partials[tile] = s;
        }

        // indices: 2KB contiguous per tile
        idxo[vblock + tid] = (float)bai;

        // z_q: 512 threads x 8 iters cover 512 rows x 32 floats, contiguous
        {
            const float4* cb4 = (const float4*)cbf;
            float4* zq4 = (float4*)zq;
            const int c = tid & 7;
#pragma unroll
            for (int it = 0; it < 8; ++it) {
                int r = it * 64 + (tid >> 3);
                int win = __float_as_int(scratch[r].z);
                float4 val = cb4[(size_t)win * 8 + c];
                zq4[(size_t)(vblock + r) * 8 + c] = val;
            }
        }
        __syncthreads();   // scratch/wsum safe to reuse for next tile
    }
}

// cold path: LDS-staged wT + full wave parallelism (R21-validated).
// Block 0 also does the final loss reduction.
__global__ __launch_bounds__(512, 2) void vq_fixup(
        const float* __restrict__ z, const float* __restrict__ cbf,
        const float* __restrict__ wT, const float* __restrict__ c32g,
        float* __restrict__ zq, float* __restrict__ idxo,
        const unsigned* __restrict__ flagcnt,
        const int* __restrict__ worklist, int wl_cap,
        const double* __restrict__ partials, float* __restrict__ loss_out) {
    __shared__ __align__(16) float wl_lds[D * N_CODES];  // 64KB
    __shared__ double w4[4];
    const int tid = threadIdx.x;

    {   // stage wT into LDS: 4096 float4 over 512 threads
        float4* s4 = (float4*)wl_lds;
        const float4* g4 = (const float4*)wT;
#pragma unroll
        for (int i = 0; i < 8; ++i) s4[i * 512 + tid] = g4[i * 512 + tid];
    }

    if (blockIdx.x == 0 && tid < 256) {         // final loss reduction
        double s = 0.0;
#pragma unroll
        for (int i = 0; i < 1024 / 256; ++i) s += partials[i * 256 + tid];
#pragma unroll
        for (int off = 32; off; off >>= 1) s += __shfl_down(s, off, 64);
        if ((tid & 63) == 0) w4[tid >> 6] = s;
    }
    __syncthreads();                            // staging + w4 visible
    if (blockIdx.x == 0 && tid == 0)
        *loss_out = (float)(1.25 * (w4[0] + w4[1] + w4[2] + w4[3])
                            / (double)ZQ_ELEMS);

    int cnt = (int)*flagcnt; if (cnt > wl_cap) cnt = wl_cap;
    const int l = tid & 63;
    const int wave = (blockIdx.x * 512 + tid) >> 6;
    const int nwaves = (gridDim.x * 512) >> 6;

    for (int e = wave; e < cnt; e += nwaves) {
        int v = worklist[e];
        const float* zv = z + (size_t)v * D;        // uniform addr -> broadcast
        float zd[D];
#pragma unroll
        for (int q = 0; q < 8; ++q) {
            float4 t = *(const float4*)(zv + q * 4);
            zd[4 * q + 0] = t.x; zd[4 * q + 1] = t.y;
            zd[4 * q + 2] = t.z; zd[4 * q + 3] = t.w;
        }
        double Ad = 0.0;
#pragma unroll
        for (int d = 0; d < D; ++d) Ad = fma((double)zd[d], (double)zd[d], Ad);
        float Af = (float)Ad;

        // 8 codes per lane: c = l + 64k ; LDS rows, lane-consecutive reads
        double bd[8];
#pragma unroll
        for (int k = 0; k < 8; ++k) bd[k] = 0.0;
#pragma unroll 4
        for (int d = 0; d < D; ++d) {
            double zdd = (double)zd[d];
            const float* wrow = wl_lds + d * N_CODES + l;
#pragma unroll
            for (int k = 0; k < 8; ++k)
                bd[k] = fma(zdd, (double)wrow[64 * k], bd[k]);
        }
        float best = 1e30f; int bi = 0;
#pragma unroll
        for (int k = 0; k < 8; ++k) {
            int c = l + 64 * k;
            float B32 = (float)bd[k];               // platonic dot
            float dq = __fadd_rn(__fsub_rn(Af, __fmul_rn(2.0f, B32)), c32g[c]);
            if (dq < best) { best = dq; bi = c; }   // k asc => c asc: first-index
        }
#pragma unroll
        for (int dd = 1; dd < 64; dd <<= 1) {
            float ob = __shfl_xor(best, dd, 64);
            int obi = __shfl_xor(bi, dd, 64);
            bool take = (ob < best) || (ob == best && obi < bi);
            best = take ? ob : best; bi = take ? obi : bi;
        }
        if (l == 0) idxo[v] = (float)bi;
        if (l < 8) {                                // one full 128B line
            float4 val = ((const float4*)cbf)[(size_t)bi * 8 + l];
            ((float4*)zq)[(size_t)v * 8 + l] = val;
        }
    }
}

extern "C" void kernel_launch(void* const* d_in, const int* in_sizes, int n_in,
                              void* d_out, int out_size, void* d_ws, size_t ws_size,
                              hipStream_t stream) {
    const float* z  = (const float*)d_in[0];
    const float* cb = (const float*)d_in[1];
    float* out  = (float*)d_out;
    float* zq   = out;
    float* idxo = out + ZQ_ELEMS;
    float* loss = out + ZQ_ELEMS + NVEC;
    unsigned* flagcnt = (unsigned*)((char*)d_ws + 8);
    float*  ww   = (float*)((char*)d_ws + 64);
    float*  ww1  = (float*)((char*)d_ws + WW1_OFF);
    half8*  bfrag = (half8*)((char*)d_ws + BFRAG_OFF);
    float*  wT   = (float*)((char*)d_ws + WT_OFF);
    const float4* stage_src = (const float4*)((char*)d_ws + WW1_OFF);
    double* partials = (double*)((char*)d_ws + PART_OFF);
    int*    worklist = (int*)((char*)d_ws + WL_OFF);
    long long avail = (long long)ws_size - WL_OFF;
    int wl_cap = avail > 0 ? (int)(avail / 4 < NVEC ? avail / 4 : NVEC) : 0;

    vq_prep<<<16, 256, 0, stream>>>(cb, ww, ww1, bfrag, wT, flagcnt);
    vq_main<<<NBLK, BT, 0, stream>>>(z, cb, stage_src, zq, idxo,
                                     partials, flagcnt, worklist, wl_cap);
    vq_fixup<<<512, 512, 0, stream>>>(z, cb, wT, ww, zq, idxo,
                                      flagcnt, worklist, wl_cap, partials, loss);
}

// Round 27
// 117.314 us; speedup vs baseline: 1.5655x; 1.0038x over previous
//
#include <hip/hip_runtime.h>

#define N_CODES 512
#define D 32
#define NVEC (8192 * 64)          // 524288 vectors
#define ZQ_ELEMS (NVEC * D)
#define BT 512                    // main block threads (8 waves share LDS image)
#define TILES 2                   // tiles of 512 rows per persistent block
#define NBLK (NVEC / (BT * TILES))   // 512 blocks = exactly 2/CU, one generation
#define MARGIN_TRIG 7e-5f
#define SA (-1.0f / 16.0f)        // B = SA*z   (power of 2, exact)
#define SB (32.0f)                // A = SB*w   -> A*B sums to -2 z.w
#define KMASK5 0xFFFFFFE0u        // clear 5 low mantissa bits for t tag

typedef _Float16 half8 __attribute__((ext_vector_type(8)));
typedef float f32x4 __attribute__((ext_vector_type(4)));

// ws: @8 uint flagcnt | @64 float ww[512] | @2112 float ww1[512]
//     | @4160 bfrag (32768) | @36928 float wT[32][512] (65536)
//     | @102464 double partials[1024] | @118848 int worklist[...]
#define WW1_OFF 2112
#define BFRAG_OFF 4160
#define WT_OFF 36928
#define PART_OFF 102464
#define WL_OFF 118848
#define STAGE_F4 2176             // (2048 + 32768) / 16, staged from ws+2112

__device__ __forceinline__ unsigned umin_(unsigned a, unsigned b) { return a < b ? a : b; }
__device__ __forceinline__ unsigned umax_(unsigned a, unsigned b) { return a > b ? a : b; }

// prep: coalesced wT float4 stores (R21-validated)
__global__ void vq_prep(const float* __restrict__ cb, float* __restrict__ ww,
                        float* __restrict__ ww1, half8* __restrict__ bfrag,
                        float* __restrict__ wT, unsigned* __restrict__ flagcnt) {
    int gid = blockIdx.x * 256 + threadIdx.x;   // 16 x 256 = 4096
    if (gid == 0) *flagcnt = 0u;
    {   // wT[d][c]: 4 consecutive c per thread -> coalesced float4 store
        int flat = gid * 4;                     // 16384 floats total
        int d = flat >> 9, c = flat & 511;
        float4 v;
        v.x = cb[(size_t)(c + 0) * D + d];
        v.y = cb[(size_t)(c + 1) * D + d];
        v.z = cb[(size_t)(c + 2) * D + d];
        v.w = cb[(size_t)(c + 3) * D + d];
        *(float4*)(wT + flat) = v;
    }
    if (gid < 2048) {                           // MFMA A-operand fragments
        int t = gid >> 6, l = gid & 63;
        int code = t * 16 + (l & 15), koff = (l >> 4) * 8;
        const float* w = cb + (size_t)code * D + koff;
        half8 h;
#pragma unroll
        for (int j = 0; j < 8; ++j) h[j] = (_Float16)(SB * w[j]);
        bfrag[t * 64 + l] = h;
    }
    if (gid < N_CODES) {                        // platonic ||w||^2 -> f32
        const float* wr = cb + (size_t)gid * D;
        double s = 0.0;
#pragma unroll
        for (int d = 0; d < D; ++d) s = fma((double)wr[d], (double)wr[d], s);
        ww[gid] = (float)s;                     // exact, for fixup formula
        ww1[gid] = (float)(1.0 + s);            // C-init (+1 => scores positive)
    }
}

// Transposed MFMA main (R20/R22/R24 hot loop) as PERSISTENT 2-tile blocks:
// 512 blocks x 512 thr, fully resident, staging amortized over 2 tiles.
__global__ __launch_bounds__(BT, 6) void vq_main(
        const float* __restrict__ z, const float* __restrict__ cbf,
        const float4* __restrict__ stage_src,   // ws+2112: ww1 | bfrag
        float* __restrict__ zq, float* __restrict__ idxo,
        double* __restrict__ partials, unsigned* __restrict__ flagcnt,
        int* __restrict__ worklist, int wl_cap) {
    __shared__ __align__(16) char smem[43008];  // cin 2K | bfrag 32K | scratch 8K
    __shared__ double wsum[8];
    const int tid = threadIdx.x;

    {   // stage ww1 + code fragments into LDS (ONCE for both tiles)
        float4* s4 = (float4*)smem;
#pragma unroll
        for (int i = 0; i < 5; ++i) {
            int k = i * BT + tid;
            if (k < STAGE_F4) s4[k] = stage_src[k];
        }
    }
    const float* lds_cin = (const float*)smem;           // 1+||w||^2 [512]
    const char* lds_bf = smem + 2048;                    // A fragments (32KB)
    float4* scratch = (float4*)(smem + 34816);           // [512] (m1,m2,idx,zz)

    const int l = tid & 63, wv = tid >> 6;
    const int g16 = l & 15, kg = l >> 4, koff = kg * 8;

    __syncthreads();   // staging visible

#pragma unroll 1
    for (int tt = 0; tt < TILES; ++tt) {
        const int tile = blockIdx.x * TILES + tt;
        const int vblock = tile * BT;                    // tile owns 512 rows
        const int vwave = vblock + wv * 64;              // wave owns 64 rows

#pragma unroll 1
        for (int vt = 0; vt < 4; ++vt) {
            const float* zp = z + (size_t)(vwave + vt * 16 + g16) * D + koff;
            float4 a0 = *(const float4*)zp;
            float4 a1 = *(const float4*)(zp + 4);
            half8 Bz;
            Bz[0] = (_Float16)(a0.x * SA); Bz[1] = (_Float16)(a0.y * SA);
            Bz[2] = (_Float16)(a0.z * SA); Bz[3] = (_Float16)(a0.w * SA);
            Bz[4] = (_Float16)(a1.x * SA); Bz[5] = (_Float16)(a1.y * SA);
            Bz[6] = (_Float16)(a1.z * SA); Bz[7] = (_Float16)(a1.w * SA);
            float ss = 0.f;                              // ||z||^2 partial
            ss = fmaf(a0.x, a0.x, ss); ss = fmaf(a0.y, a0.y, ss);
            ss = fmaf(a0.z, a0.z, ss); ss = fmaf(a0.w, a0.w, ss);
            ss = fmaf(a1.x, a1.x, ss); ss = fmaf(a1.y, a1.y, ss);
            ss = fmaf(a1.z, a1.z, ss); ss = fmaf(a1.w, a1.w, ss);
            // ss stays PARTIAL; the cross-kg butterfly sums it exactly once.

            unsigned m1c[4], m2c[4];
#pragma unroll
            for (int r = 0; r < 4; ++r) { m1c[r] = 0xFFFFFFFFu; m2c[r] = 0xFFFFFFFFu; }

            // fully unrolled t-pair loop => t literal => inline-const tag
#pragma unroll
            for (int tp = 0; tp < 16; ++tp) {
                half8 W0 = *(const half8*)(lds_bf + (2 * tp) * 1024 + l * 16);
                half8 W1 = *(const half8*)(lds_bf + (2 * tp + 1) * 1024 + l * 16);
                f32x4 cv0 = *(const f32x4*)(lds_cin + (2 * tp) * 16 + kg * 4);
                f32x4 cv1 = *(const f32x4*)(lds_cin + (2 * tp + 1) * 16 + kg * 4);
                f32x4 acc0 = __builtin_amdgcn_mfma_f32_16x16x32_f16(W0, Bz, cv0, 0, 0, 0);
                f32x4 acc1 = __builtin_amdgcn_mfma_f32_16x16x32_f16(W1, Bz, cv1, 0, 0, 0);
#pragma unroll
                for (int r = 0; r < 4; ++r) {
                    unsigned k0 = (__float_as_uint(acc0[r]) & KMASK5) | (unsigned)(2 * tp);
                    unsigned k1 = (__float_as_uint(acc1[r]) & KMASK5) | (unsigned)(2 * tp + 1);
                    unsigned med;
                    asm("v_med3_u32 %0, %1, %2, %3"
                        : "=v"(med) : "v"(m1c[r]), "v"(k0), "v"(k1));
                    asm("v_min3_u32 %0, %1, %2, %3"
                        : "=v"(m1c[r]) : "v"(m1c[r]), "v"(k0), "v"(k1));
                    m2c[r] = umin_(m2c[r], med);
                }
            }

            // merge the 4 chains -> lane-local (b1, b2, rwin)
            unsigned a01 = umin_(m1c[0], m1c[1]), x01 = umax_(m1c[0], m1c[1]);
            unsigned a23 = umin_(m1c[2], m1c[3]), x23 = umax_(m1c[2], m1c[3]);
            unsigned b1 = umin_(a01, a23);
            unsigned sec = umin_(umax_(a01, a23), umin_(x01, x23));
            unsigned m2all = umin_(umin_(m2c[0], m2c[1]), umin_(m2c[2], m2c[3]));
            unsigned b2 = umin_(sec, m2all);
            int rwin = (m1c[0] == b1) ? 0
                     : (m1c[1] == b1) ? 1
                     : (m1c[2] == b1) ? 2 : 3;
            unsigned mymin = b1;

            // cross-kg reduce (lanes +-16, +-32): b1, b2, ss
#pragma unroll
            for (int dd = 16; dd <= 32; dd <<= 1) {
                unsigned o1 = __shfl_xor(b1, dd, 64);
                unsigned o2 = __shfl_xor(b2, dd, 64);
                float os = __shfl_xor(ss, dd, 64);
                b2 = umin_(umin_(b2, o2), umax_(b1, o1));
                b1 = umin_(b1, o1);
                ss += os;
            }
            // winner kg via ballot (lowest kg on tie), then winner lane's r
            unsigned long long bal =
                __ballot(mymin == b1) & (0x0001000100010001ull << g16);
            int firstl = __builtin_ctzll(bal);
            int rw = __shfl(rwin, firstl, 64);
            int code = (int)(b1 & 31u) * 16 + (firstl >> 4) * 4 + rw;
            if (kg == 0)
                scratch[wv * 64 + vt * 16 + g16] =
                    make_float4(__uint_as_float(b1 & KMASK5),
                                __uint_as_float(b2 & KMASK5),
                                __int_as_float(code), ss);
        }
        __syncthreads();

        // ---- per-tile epilogue (block scope) ----
        float4 my = scratch[tid];                // row tid of this tile
        int bai = __float_as_int(my.z);

        // near-tie rows -> dense worklist (one uint atomic per wave)
        {
            bool flag = (my.y - my.x) <= MARGIN_TRIG;
            unsigned long long mask = __ballot(flag);
            if (mask) {
                int base = 0;
                if (l == 0) base = (int)atomicAdd(flagcnt, (unsigned)__popcll(mask));
                base = __shfl(base, 0, 64);
                if (flag) {
                    int pos = base + (int)__popcll(mask & ((1ull << l) - 1ull));
                    if (pos < wl_cap) worklist[pos] = vblock + tid;
                }
            }
        }

        // loss: ||z-q||^2 = ||z||^2 + (m1 - 1)
        {
            double contrib = ((double)my.x - 1.0) + (double)my.w;
#pragma unroll
            for (int off = 32; off; off >>= 1) contrib += __shfl_down(contrib, off, 64);
            if (l == 0) wsum[wv] = contrib;
        }
        __syncthreads();
        if (tid == 0) {
            double s = 0.0;
#pragma unroll
            for (int w = 0; w < 8; ++w) s += wsum[w];
            partials[tile] = s;
        }

        // indices: 2KB contiguous per tile
        idxo[vblock + tid] = (float)bai;

        // z_q: 512 threads x 8 iters cover 512 rows x 32 floats, contiguous
        {
            const float4* cb4 = (const float4*)cbf;
            float4* zq4 = (float4*)zq;
            const int c = tid & 7;
#pragma unroll
            for (int it = 0; it < 8; ++it) {
                int r = it * 64 + (tid >> 3);
                int win = __float_as_int(scratch[r].z);
                float4 val = cb4[(size_t)win * 8 + c];
                zq4[(size_t)(vblock + r) * 8 + c] = val;
            }
        }
        __syncthreads();   // scratch/wsum safe to reuse for next tile
    }
}

// cold path: LDS-staged wT + full wave parallelism (R21-validated).
// Block 0 also does the final loss reduction.
__global__ __launch_bounds__(512, 2) void vq_fixup(
        const float* __restrict__ z, const float* __restrict__ cbf,
        const float* __restrict__ wT, const float* __restrict__ c32g,
        float* __restrict__ zq, float* __restrict__ idxo,
        const unsigned* __restrict__ flagcnt,
        const int* __restrict__ worklist, int wl_cap,
        const double* __restrict__ partials, float* __restrict__ loss_out) {
    __shared__ __align__(16) float wl_lds[D * N_CODES];  // 64KB
    __shared__ double w4[4];
    const int tid = threadIdx.x;

    {   // stage wT into LDS: 4096 float4 over 512 threads
        float4* s4 = (float4*)wl_lds;
        const float4* g4 = (const float4*)wT;
#pragma unroll
        for (int i = 0; i < 8; ++i) s4[i * 512 + tid] = g4[i * 512 + tid];
    }

    if (blockIdx.x == 0 && tid < 256) {         // final loss reduction
        double s = 0.0;
#pragma unroll
        for (int i = 0; i < 1024 / 256; ++i) s += partials[i * 256 + tid];
#pragma unroll
        for (int off = 32; off; off >>= 1) s += __shfl_down(s, off, 64);
        if ((tid & 63) == 0) w4[tid >> 6] = s;
    }
    __syncthreads();                            // staging + w4 visible
    if (blockIdx.x == 0 && tid == 0)
        *loss_out = (float)(1.25 * (w4[0] + w4[1] + w4[2] + w4[3])
                            / (double)ZQ_ELEMS);

    int cnt = (int)*flagcnt; if (cnt > wl_cap) cnt = wl_cap;
    const int l = tid & 63;
    const int wave = (blockIdx.x * 512 + tid) >> 6;
    const int nwaves = (gridDim.x * 512) >> 6;

    for (int e = wave; e < cnt; e += nwaves) {
        int v = worklist[e];
        const float* zv = z + (size_t)v * D;        // uniform addr -> broadcast
        float zd[D];
#pragma unroll
        for (int q = 0; q < 8; ++q) {
            float4 t = *(const float4*)(zv + q * 4);
            zd[4 * q + 0] = t.x; zd[4 * q + 1] = t.y;
            zd[4 * q + 2] = t.z; zd[4 * q + 3] = t.w;
        }
        double Ad = 0.0;
#pragma unroll
        for (int d = 0; d < D; ++d) Ad = fma((double)zd[d], (double)zd[d], Ad);
        float Af = (float)Ad;

        // 8 codes per lane: c = l + 64k ; LDS rows, lane-consecutive reads
        double bd[8];
#pragma unroll
        for (int k = 0; k < 8; ++k) bd[k] = 0.0;
#pragma unroll 4
        for (int d = 0; d < D; ++d) {
            double zdd = (double)zd[d];
            const float* wrow = wl_lds + d * N_CODES + l;
#pragma unroll
            for (int k = 0; k < 8; ++k)
                bd[k] = fma(zdd, (double)wrow[64 * k], bd[k]);
        }
        float best = 1e30f; int bi = 0;
#pragma unroll
        for (int k = 0; k < 8; ++k) {
            int c = l + 64 * k;
            float B32 = (float)bd[k];               // platonic dot
            float dq = __fadd_rn(__fsub_rn(Af, __fmul_rn(2.0f, B32)), c32g[c]);
            if (dq < best) { best = dq; bi = c; }   // k asc => c asc: first-index
        }
#pragma unroll
        for (int dd = 1; dd < 64; dd <<= 1) {
            float ob = __shfl_xor(best, dd, 64);
            int obi = __shfl_xor(bi, dd, 64);
            bool take = (ob < best) || (ob == best && obi < bi);
            best = take ? ob : best; bi = take ? obi : bi;
        }
        if (l == 0) idxo[v] = (float)bi;
        if (l < 8) {                                // one full 128B line
            float4 val = ((const float4*)cbf)[(size_t)bi * 8 + l];
            ((float4*)zq)[(size_t)v * 8 + l] = val;
        }
    }
}

extern "C" void kernel_launch(void* const* d_in, const int* in_sizes, int n_in,
                              void* d_out, int out_size, void* d_ws, size_t ws_size,
                              hipStream_t stream) {
    const float* z  = (const float*)d_in[0];
    const float* cb = (const float*)d_in[1];
    float* out  = (float*)d_out;
    float* zq   = out;
    float* idxo = out + ZQ_ELEMS;
    float* loss = out + ZQ_ELEMS + NVEC;
    unsigned* flagcnt = (unsigned*)((char*)d_ws + 8);
    float*  ww   = (float*)((char*)d_ws + 64);
    float*  ww1  = (float*)((char*)d_ws + WW1_OFF);
    half8*  bfrag = (half8*)((char*)d_ws + BFRAG_OFF);
    float*  wT   = (float*)((char*)d_ws + WT_OFF);
    const float4* stage_src = (const float4*)((char*)d_ws + WW1_OFF);
    double* partials = (double*)((char*)d_ws + PART_OFF);
    int*    worklist = (int*)((char*)d_ws + WL_OFF);
    long long avail = (long long)ws_size - WL_OFF;
    int wl_cap = avail > 0 ? (int)(avail / 4 < NVEC ? avail / 4 : NVEC) : 0;

    vq_prep<<<16, 256, 0, stream>>>(cb, ww, ww1, bfrag, wT, flagcnt);
    vq_main<<<NBLK, BT, 0, stream>>>(z, cb, stage_src, zq, idxo,
                                     partials, flagcnt, worklist, wl_cap);
    vq_fixup<<<512, 512, 0, stream>>>(z, cb, wT, ww, zq, idxo,
                                      flagcnt, worklist, wl_cap, partials, loss);
}